// Round 2
// baseline (334.372 us; speedup 1.0000x reference)
//
#include <hip/hip_runtime.h>
#include <cstdint>
#include <cstddef>

#define INPUT_DIM 784
#define HIDDEN    4096
#define BATCH     64
#define T_STEPS   30
#define N0 (BATCH*INPUT_DIM)   // 50176
#define N1 (BATCH*HIDDEN)      // 262144
#define M_ROWS (T_STEPS*BATCH) // 1920
#define NDIG 4
#define MB_CNT (M_ROWS/32)     // 60
#define KC1 25                 // gemm1 k-chunks (784 padded to 800)
#define KC2 128                // gemm2 k-chunks

typedef int v4i  __attribute__((ext_vector_type(4)));
typedef int v16i __attribute__((ext_vector_type(16)));

// ---------------- max(x) reduction (unchanged, passing) --------------------
__global__ __launch_bounds__(256) void max_kernel(const float* __restrict__ x,
                                                  unsigned* __restrict__ maxbits) {
    int i = blockIdx.x * 256 + threadIdx.x;
    float v = (i < N0) ? x[i] : 0.0f;
    #pragma unroll
    for (int off = 32; off > 0; off >>= 1)
        v = fmaxf(v, __shfl_down(v, off, 64));
    __shared__ float sm[4];
    int lane = threadIdx.x & 63;
    int wv   = threadIdx.x >> 6;
    if (lane == 0) sm[wv] = v;
    __syncthreads();
    if (threadIdx.x == 0) {
        float m = fmaxf(fmaxf(sm[0], sm[1]), fmaxf(sm[2], sm[3]));
        atomicMax(maxbits, __float_as_uint(m));
    }
}

// ---------------- layer 0 LIF: same math (passing), spikes -> A-fragments --
// AF1[kc][mb][lane][16], lane=(b&31)|(((j>>4)&1)<<5), mb=2t+(b>>5), byte=j&15.
__global__ __launch_bounds__(256) void lif0_kernel(const float* __restrict__ x,
                                                   const unsigned* __restrict__ maxbits,
                                                   uint8_t* __restrict__ AF1,
                                                   float* __restrict__ out0) {
    int j = blockIdx.x * 256 + threadIdx.x;   // input-dim index
    int b = blockIdx.y;                        // batch
    if (j >= INPUT_DIM) return;
    float mx = fmaxf(__uint_as_float(*maxbits), 1e-12f);
    float xs = __fmul_rn(__fdiv_rn(x[b * INPUT_DIM + j], mx), 16.0f);
    int kc = j >> 5;
    int lane = (b & 31) | (((j >> 4) & 1) << 5);
    size_t base = (((size_t)(kc * MB_CNT + (b >> 5)) * 64 + lane) << 4) + (j & 15);
    float v = 0.0f;
    int cnt = 0;
    #pragma unroll
    for (int t = 0; t < T_STEPS; ++t) {
        v = __fadd_rn(__fmul_rn(v, 0.99f), xs);
        int s = (v >= 0.5f) ? 1 : 0;
        cnt += s;
        v = s ? 0.0f : v;
        AF1[base + (size_t)t * 2048] = (uint8_t)s;
    }
    out0[b * INPUT_DIM + j] = (float)cnt / 30.0f;
}

// ---------------- W -> 4 digit planes in MFMA B-fragment order -------------
// q = round(W * scale); 4 signed base-256 digits; per-elem err <= 1/(2*scale).
// BF[nb][kc][d][lane][16]; rows k >= Krows are zero (gemm1 K padding).
__global__ __launch_bounds__(256) void digitize_kernel(const float* __restrict__ W,
                                                       int8_t* __restrict__ BF,
                                                       int Krows, int KC, double scale) {
    __shared__ float tile[32][33];
    const int nb = blockIdx.x, kc = blockIdx.y;
    const int tid = threadIdx.x;
    {
        int r  = tid >> 3;
        int c4 = (tid & 7) << 2;
        int k  = kc * 32 + r;
        float4 w4 = make_float4(0.f, 0.f, 0.f, 0.f);
        if (k < Krows)
            w4 = *(const float4*)&W[(size_t)k * HIDDEN + nb * 32 + c4];
        tile[r][c4]     = w4.x;
        tile[r][c4 + 1] = w4.y;
        tile[r][c4 + 2] = w4.z;
        tile[r][c4 + 3] = w4.w;
    }
    __syncthreads();
    const int d    = tid >> 6;        // wave -> digit plane
    const int lane = tid & 63;
    const int nl   = lane & 31;
    const int kh   = (lane >> 5) << 4;
    char dig[16];
    #pragma unroll
    for (int jj = 0; jj < 16; ++jj) {
        double w = (double)tile[kh + jj][nl];
        long long q = __double2ll_rn(w * scale);
        int dd = 0;
        #pragma unroll
        for (int dd_i = 0; dd_i <= 3; ++dd_i) {
            dd = (int)(((q + 128) & 255) - 128);
            q = (q - (long long)dd) >> 8;
            if (dd_i == d) break;
        }
        dig[jj] = (char)dd;
    }
    *(int4*)&BF[((((size_t)nb * KC + kc) * NDIG + d) << 10) + (lane << 4)] =
        *(int4*)&dig[0];
}

// ---------------- exact i8-digit streaming GEMM (both layers) --------------
// C(1920 x 4096 f64) = A(binary) @ W, 4 digit planes, no LDS, no barriers.
// DEPTH-3 register pipeline. Post-mortem R1: the depth-2 unroll-2 rotation's
// true cover was ONE scalar iteration (~690 cyc wall): LOAD(0)@body k is
// consumed at MFMA(0)@body k+1 with only MFMA(1)+LOAD(1) in between. FETCH
// (155 MB vs 72 MB compulsory) shows much of B streams from HBM (~900-1100
// cyc loaded latency) -> ~350 cyc stall per wait, 2 waits/body = the
// measured 790 cyc/iter gap (MfmaUtil pinned at 40%). Three slots make the
// cover ~2 scalar iterations (~1400 cyc) > worst-case latency. Cost: +24
// VGPR (slot regs 48->72); ~120 VGPR + 128 acc = ~248/wave keeps 2
// waves/SIMD (512-reg pool). Slot index compile-time via groups-of-3 +
// constexpr remainder tails (KC=128 -> R=2, KC=25 -> R=1); no runtime
// array indexing. XCD-clustered swizzle unchanged (8 MB B/XCD).
#define MFMA_GRP(A0, A1, B0, B1, B2, B3)                                        \
    acc[0][0] = __builtin_amdgcn_mfma_i32_32x32x32_i8(A0, B0, acc[0][0], 0, 0, 0); \
    acc[1][0] = __builtin_amdgcn_mfma_i32_32x32x32_i8(A1, B0, acc[1][0], 0, 0, 0); \
    acc[0][1] = __builtin_amdgcn_mfma_i32_32x32x32_i8(A0, B1, acc[0][1], 0, 0, 0); \
    acc[1][1] = __builtin_amdgcn_mfma_i32_32x32x32_i8(A1, B1, acc[1][1], 0, 0, 0); \
    acc[0][2] = __builtin_amdgcn_mfma_i32_32x32x32_i8(A0, B2, acc[0][2], 0, 0, 0); \
    acc[1][2] = __builtin_amdgcn_mfma_i32_32x32x32_i8(A1, B2, acc[1][2], 0, 0, 0); \
    acc[0][3] = __builtin_amdgcn_mfma_i32_32x32x32_i8(A0, B3, acc[0][3], 0, 0, 0); \
    acc[1][3] = __builtin_amdgcn_mfma_i32_32x32x32_i8(A1, B3, acc[1][3], 0, 0, 0)

#define LOAD_SLOT(S)                                                            \
    As[S][0] = *(const v4i*)ap;          As[S][1] = *(const v4i*)(ap + 1024);   \
    Bs[S][0] = *(const v4i*)bp;          Bs[S][1] = *(const v4i*)(bp + 1024);   \
    Bs[S][2] = *(const v4i*)(bp + 2048); Bs[S][3] = *(const v4i*)(bp + 3072)

#define ADV() do { ap += astride; bp += bstride; } while (0)

#define MFMA_SLOT(S) MFMA_GRP(As[S][0], As[S][1], Bs[S][0], Bs[S][1], Bs[S][2], Bs[S][3])

template <int KC>
__global__ __launch_bounds__(256, 2) void gemm_i8_kernel(const int8_t* __restrict__ AF,
                                                         const int8_t* __restrict__ BF,
                                                         double* __restrict__ C,
                                                         double scale) {
    const int tid  = threadIdx.x;
    const int wave = tid >> 6, lane = tid & 63;
    const int i  = blockIdx.x;
    const int bx = i >> 6;                            // 0..14
    const int by = ((i & 7) << 3) | ((i >> 3) & 7);   // XCD-clustered n-block
    const int nb  = by * 2 + (wave & 1);
    const int msb = (wave >> 1) * 2;
    const int mb0 = bx * 4 + msb;

    const int8_t* ap = AF + (((size_t)mb0 * 64 + lane) << 4);
    const int8_t* bp = BF + (((size_t)nb * KC * NDIG) << 10) + (lane << 4);
    const int astride = MB_CNT * 64 * 16;   // 61440
    const int bstride = NDIG * 1024;        // 4096

    v16i acc[2][4] = {};
    v4i As[3][2], Bs[3][4];

    LOAD_SLOT(0); ADV();                    // chunk 0
    LOAD_SLOT(1); ADV();                    // chunk 1
    LOAD_SLOT(2);                           // chunk 2

    // steady state: iter kc consumes slot kc%3 (loaded 3 iters ago ->
    // wait vmcnt(12), ~2 scalar iters of wall cover), then prefetches
    // chunk kc+3 into the same slot. Loads cover chunks 3 .. KC-1.
    constexpr int G = (KC - 3) / 3;         // full groups (iters 0..3G-1)
    constexpr int R = (KC - 3) % 3;         // leftover prefetches
    for (int g = 0; g < G; ++g) {
        MFMA_SLOT(0); ADV(); LOAD_SLOT(0);
        MFMA_SLOT(1); ADV(); LOAD_SLOT(1);
        MFMA_SLOT(2); ADV(); LOAD_SLOT(2);
    }
    if constexpr (R == 2) {                 // KC=128: consume 123..127
        MFMA_SLOT(0); ADV(); LOAD_SLOT(0);  // consume 3G,   load KC-2
        MFMA_SLOT(1); ADV(); LOAD_SLOT(1);  // consume 3G+1, load KC-1
        MFMA_SLOT(2);                       // consume 3G+2
        MFMA_SLOT(0);                       // consume KC-2
        MFMA_SLOT(1);                       // consume KC-1
    } else if constexpr (R == 1) {          // KC=25: consume 21..24
        MFMA_SLOT(0); ADV(); LOAD_SLOT(0);  // consume 3G,   load KC-1
        MFMA_SLOT(1);                       // consume 3G+1
        MFMA_SLOT(2);                       // consume 3G+2
        MFMA_SLOT(0);                       // consume KC-1
    } else {
        MFMA_SLOT(0);
        MFMA_SLOT(1);
        MFMA_SLOT(2);
    }

    // epilogue: C/D layout col=lane&31, row=(r&3)+8*(r>>2)+4*(lane>>5)
    const int col = lane & 31;
    const int rb  = (lane >> 5) << 2;
    const int n_g = by * 64 + (wave & 1) * 32 + col;
    #pragma unroll
    for (int s = 0; s < 2; ++s) {
        const int m_base = bx * 128 + (msb + s) * 32;
        #pragma unroll
        for (int r = 0; r < 16; ++r) {
            int row = (r & 3) + 8 * (r >> 2) + rb;
            long long v = 0;
            #pragma unroll
            for (int d = 3; d >= 0; --d) v = (v << 8) + (long long)acc[s][d][r];
            C[(size_t)(m_base + row) * HIDDEN + n_g] = (double)v * scale;
        }
    }
}

// ---------------- layer 1 LIF: f64 currents, spikes -> A-fragments ---------
__global__ __launch_bounds__(256) void lif1_kernel(const double* __restrict__ CUR,
                                                   uint8_t* __restrict__ AF,
                                                   float* __restrict__ out1) {
    int e = blockIdx.x * 256 + threadIdx.x;
    int b = e >> 12;
    int j = e & 4095;
    int kc = j >> 5;
    int lane = (b & 31) | (((j >> 4) & 1) << 5);
    size_t base = (((size_t)(kc * MB_CNT + (b >> 5)) * 64 + lane) << 4) + (j & 15);
    double v = 0.0;
    int cnt = 0;
    #pragma unroll
    for (int t = 0; t < T_STEPS; ++t) {
        double cur = CUR[(size_t)t * N1 + e];
        v = __dadd_rn(__dmul_rn(v, 0.99), cur);
        int s = (v >= 0.5) ? 1 : 0;
        cnt += s;
        v = s ? 0.0 : v;
        AF[base + (size_t)t * 2048] = (uint8_t)s;
    }
    out1[e] = (float)cnt / 30.0f;
}

// ---------------- layer 2 LIF in fp64 (unchanged, passing) -----------------
__global__ __launch_bounds__(256) void lif2_kernel(const double* __restrict__ CUR,
                                                   float* __restrict__ out2) {
    int e = blockIdx.x * 256 + threadIdx.x;
    double v = 0.0;
    int cnt = 0;
    #pragma unroll
    for (int t = 0; t < T_STEPS; ++t) {
        double cur = CUR[(size_t)t * N1 + e];
        v = __dadd_rn(__dmul_rn(v, 0.99), cur);
        int s = (v >= 0.5) ? 1 : 0;
        cnt += s;
        v = s ? 0.0 : v;
    }
    out2[e] = (float)cnt / 30.0f;
}

extern "C" void kernel_launch(void* const* d_in, const int* in_sizes, int n_in,
                              void* d_out, int out_size, void* d_ws, size_t ws_size,
                              hipStream_t stream) {
    const float* x  = (const float*)d_in[0];
    const float* W1 = (const float*)d_in[1];   // 784 x 4096
    const float* W2 = (const float*)d_in[2];   // 4096 x 4096
    float* out = (float*)d_out;
    char*  ws  = (char*)d_ws;

    // workspace (~153 MB):
    // [maxbits 256B][AF1 1.54MB][BF1 12.8MB][AF2 7.86MB][BF2 64MB][CURd 62.9MB]
    const size_t AF1_SZ = (size_t)KC1 * MB_CNT * 1024;           // 1,536,000
    const size_t BF1_SZ = (size_t)128 * KC1 * NDIG * 1024;       // 12.8 MB
    const size_t AF2_SZ = (size_t)KC2 * MB_CNT * 1024;           // 7.86 MB
    const size_t BF2_SZ = (size_t)128 * KC2 * NDIG * 1024;       // 64 MB
    unsigned* maxbits = (unsigned*)ws;
    uint8_t*  AF1 = (uint8_t*)(ws + 256);
    int8_t*   BF1 = (int8_t*)(AF1 + AF1_SZ);
    uint8_t*  AF2 = (uint8_t*)(BF1 + BF1_SZ);
    int8_t*   BF2 = (int8_t*)(AF2 + AF2_SZ);
    double*   CURd = (double*)((char*)BF2 + BF2_SZ);

    float* out0 = out;
    float* out1 = out + N0;
    float* out2 = out + N0 + N1;

    hipMemsetAsync(maxbits, 0, 4, stream);
    hipMemsetAsync(AF1, 0, AF1_SZ, stream);   // K-padding rows 784..799 stay 0
    max_kernel <<<(N0 + 255) / 256, 256, 0, stream>>>(x, maxbits);
    lif0_kernel<<<dim3(4, BATCH), 256, 0, stream>>>(x, maxbits, AF1, out0);
    digitize_kernel<<<dim3(128, KC1), 256, 0, stream>>>(W1, BF1, INPUT_DIM, KC1,
                                                        4294967296.0);      // 2^32
    digitize_kernel<<<dim3(128, KC2), 256, 0, stream>>>(W2, BF2, HIDDEN, KC2,
                                                        8589934592.0);      // 2^33
    gemm_i8_kernel<KC1><<<960, 256, 0, stream>>>((const int8_t*)AF1, BF1, CURd,
                                                 2.3283064365386963e-10);   // 2^-32
    lif1_kernel<<<N1 / 256, 256, 0, stream>>>(CURd, AF2, out1);
    gemm_i8_kernel<KC2><<<960, 256, 0, stream>>>((const int8_t*)AF2, BF2, CURd,
                                                 1.1641532182693481e-10);   // 2^-33
    lif2_kernel<<<N1 / 256, 256, 0, stream>>>(CURd, out2);
}

// Round 3
// 327.505 us; speedup vs baseline: 1.0210x; 1.0210x over previous
//
#include <hip/hip_runtime.h>
#include <cstdint>
#include <cstddef>

#define INPUT_DIM 784
#define HIDDEN    4096
#define BATCH     64
#define T_STEPS   30
#define N0 (BATCH*INPUT_DIM)   // 50176
#define N1 (BATCH*HIDDEN)      // 262144
#define M_ROWS (T_STEPS*BATCH) // 1920
#define NDIG 4
#define MB_CNT (M_ROWS/32)     // 60
#define KC1 25                 // gemm1 k-chunks (784 padded to 800)
#define KC2 128                // gemm2 k-chunks

typedef int v4i  __attribute__((ext_vector_type(4)));
typedef int v16i __attribute__((ext_vector_type(16)));

// ---------------- max(x) reduction (unchanged, passing) --------------------
__global__ __launch_bounds__(256) void max_kernel(const float* __restrict__ x,
                                                  unsigned* __restrict__ maxbits) {
    int i = blockIdx.x * 256 + threadIdx.x;
    float v = (i < N0) ? x[i] : 0.0f;
    #pragma unroll
    for (int off = 32; off > 0; off >>= 1)
        v = fmaxf(v, __shfl_down(v, off, 64));
    __shared__ float sm[4];
    int lane = threadIdx.x & 63;
    int wv   = threadIdx.x >> 6;
    if (lane == 0) sm[wv] = v;
    __syncthreads();
    if (threadIdx.x == 0) {
        float m = fmaxf(fmaxf(sm[0], sm[1]), fmaxf(sm[2], sm[3]));
        atomicMax(maxbits, __float_as_uint(m));
    }
}

// ---------------- layer 0 LIF: same math (passing), spikes -> A-fragments --
// AF1[kc][mb][lane][16], lane=(b&31)|(((j>>4)&1)<<5), mb=2t+(b>>5), byte=j&15.
__global__ __launch_bounds__(256) void lif0_kernel(const float* __restrict__ x,
                                                   const unsigned* __restrict__ maxbits,
                                                   uint8_t* __restrict__ AF1,
                                                   float* __restrict__ out0) {
    int j = blockIdx.x * 256 + threadIdx.x;   // input-dim index
    int b = blockIdx.y;                        // batch
    if (j >= INPUT_DIM) return;
    float mx = fmaxf(__uint_as_float(*maxbits), 1e-12f);
    float xs = __fmul_rn(__fdiv_rn(x[b * INPUT_DIM + j], mx), 16.0f);
    int kc = j >> 5;
    int lane = (b & 31) | (((j >> 4) & 1) << 5);
    size_t base = (((size_t)(kc * MB_CNT + (b >> 5)) * 64 + lane) << 4) + (j & 15);
    float v = 0.0f;
    int cnt = 0;
    #pragma unroll
    for (int t = 0; t < T_STEPS; ++t) {
        v = __fadd_rn(__fmul_rn(v, 0.99f), xs);
        int s = (v >= 0.5f) ? 1 : 0;
        cnt += s;
        v = s ? 0.0f : v;
        AF1[base + (size_t)t * 2048] = (uint8_t)s;
    }
    out0[b * INPUT_DIM + j] = (float)cnt / 30.0f;
}

// ---------------- W -> 4 digit planes in MFMA B-fragment order -------------
// q = round(W * scale); 4 signed base-256 digits; per-elem err <= 1/(2*scale).
// BF[nb][kc][d][lane][16]; rows k >= Krows are zero (gemm1 K padding).
__global__ __launch_bounds__(256) void digitize_kernel(const float* __restrict__ W,
                                                       int8_t* __restrict__ BF,
                                                       int Krows, int KC, double scale) {
    __shared__ float tile[32][33];
    const int nb = blockIdx.x, kc = blockIdx.y;
    const int tid = threadIdx.x;
    {
        int r  = tid >> 3;
        int c4 = (tid & 7) << 2;
        int k  = kc * 32 + r;
        float4 w4 = make_float4(0.f, 0.f, 0.f, 0.f);
        if (k < Krows)
            w4 = *(const float4*)&W[(size_t)k * HIDDEN + nb * 32 + c4];
        tile[r][c4]     = w4.x;
        tile[r][c4 + 1] = w4.y;
        tile[r][c4 + 2] = w4.z;
        tile[r][c4 + 3] = w4.w;
    }
    __syncthreads();
    const int d    = tid >> 6;        // wave -> digit plane
    const int lane = tid & 63;
    const int nl   = lane & 31;
    const int kh   = (lane >> 5) << 4;
    char dig[16];
    #pragma unroll
    for (int jj = 0; jj < 16; ++jj) {
        double w = (double)tile[kh + jj][nl];
        long long q = __double2ll_rn(w * scale);
        int dd = 0;
        #pragma unroll
        for (int dd_i = 0; dd_i <= 3; ++dd_i) {
            dd = (int)(((q + 128) & 255) - 128);
            q = (q - (long long)dd) >> 8;
            if (dd_i == d) break;
        }
        dig[jj] = (char)dd;
    }
    *(int4*)&BF[((((size_t)nb * KC + kc) * NDIG + d) << 10) + (lane << 4)] =
        *(int4*)&dig[0];
}

// ---------------- exact i8-digit streaming GEMM (both layers) --------------
// C(1920 x 4096 f64) = A(binary) @ W, 4 digit planes, no LDS, no barriers.
//
// Post-mortem R2: depth-3 regressed (145us, FETCH 166MB) -> the stall is NOT
// load latency (cover was ~2900 cyc). Loads take 1000s of cycles because the
// L2-miss path is SATURATED: the old swizzle gave each XCD an 8MB B-slice vs
// its 4MB L2, so B-reads of drifting blocks miss L2, queue at LLC/HBM MSHRs
// (FETCH 166MB = 2.6x B's 64MB compulsory), and back-pressure all VMEM
// regardless of software pipeline depth.
//
// Fix: PHASE-GROUPED XCD MAPPING. Two dispatch-ordered phases of 480 blocks
// (machine fills 512 slots, so each phase runs nearly alone). Within a phase
// each XCD (i&7) owns exactly 4 by-windows = 4MB of B = its L2 capacity; all
// 60 of an XCD's phase-blocks are co-resident, so after first touch B-reads
// are L2 hits (~200 cyc). A's per-chunk working set is 60KB (streams). GEMM
// core reverts to depth-2 copy-free rotation (96 VGPR): one-iteration cover
// (~690 cyc) is ample for L2-hit latency, and fewer outstanding loads means
// less MSHR pressure.
#define MFMA_GRP(A0, A1, B0, B1, B2, B3)                                        \
    acc[0][0] = __builtin_amdgcn_mfma_i32_32x32x32_i8(A0, B0, acc[0][0], 0, 0, 0); \
    acc[1][0] = __builtin_amdgcn_mfma_i32_32x32x32_i8(A1, B0, acc[1][0], 0, 0, 0); \
    acc[0][1] = __builtin_amdgcn_mfma_i32_32x32x32_i8(A0, B1, acc[0][1], 0, 0, 0); \
    acc[1][1] = __builtin_amdgcn_mfma_i32_32x32x32_i8(A1, B1, acc[1][1], 0, 0, 0); \
    acc[0][2] = __builtin_amdgcn_mfma_i32_32x32x32_i8(A0, B2, acc[0][2], 0, 0, 0); \
    acc[1][2] = __builtin_amdgcn_mfma_i32_32x32x32_i8(A1, B2, acc[1][2], 0, 0, 0); \
    acc[0][3] = __builtin_amdgcn_mfma_i32_32x32x32_i8(A0, B3, acc[0][3], 0, 0, 0); \
    acc[1][3] = __builtin_amdgcn_mfma_i32_32x32x32_i8(A1, B3, acc[1][3], 0, 0, 0)

#define LOAD_SLOT(S)                                                            \
    As[S][0] = *(const v4i*)ap;          As[S][1] = *(const v4i*)(ap + 1024);   \
    Bs[S][0] = *(const v4i*)bp;          Bs[S][1] = *(const v4i*)(bp + 1024);   \
    Bs[S][2] = *(const v4i*)(bp + 2048); Bs[S][3] = *(const v4i*)(bp + 3072)

#define MFMA_SLOT(S) MFMA_GRP(As[S][0], As[S][1], Bs[S][0], Bs[S][1], Bs[S][2], Bs[S][3])

template <int KC>
__global__ __launch_bounds__(256, 2) void gemm_i8_kernel(const int8_t* __restrict__ AF,
                                                         const int8_t* __restrict__ BF,
                                                         double* __restrict__ C,
                                                         double scale) {
    const int tid  = threadIdx.x;
    const int wave = tid >> 6, lane = tid & 63;
    const int i  = blockIdx.x;
    // phase-grouped XCD mapping: i = p*480 + j; xcd = j&7 owns by-windows
    // p*32 + 4*xcd .. p*32 + 4*xcd+3 (4MB of B = L2 size); bx = j>>5 (0..14).
    const int p  = (i >= 480) ? 1 : 0;
    const int j  = i - p * 480;
    const int bx = j >> 5;                                   // 0..14
    const int by = p * 32 + ((j & 7) << 2) + ((j >> 3) & 3); // 0..63
    const int nb  = by * 2 + (wave & 1);
    const int msb = (wave >> 1) * 2;
    const int mb0 = bx * 4 + msb;

    const int8_t* ap = AF + (((size_t)mb0 * 64 + lane) << 4);
    const int8_t* bp = BF + (((size_t)nb * KC * NDIG) << 10) + (lane << 4);
    const int astride = MB_CNT * 64 * 16;   // 61440
    const int bstride = NDIG * 1024;        // 4096

    v16i acc[2][4] = {};
    v4i As[2][2], Bs[2][4];

    LOAD_SLOT(0);                           // chunk 0
    ap += astride; bp += bstride;
    LOAD_SLOT(1);                           // chunk 1

    // depth-2 copy-free: iter kc consumes slot kc&1 (loaded 2 iters ago),
    // then prefetches chunk kc+2 into the same slot. Even iteration count so
    // slot indices stay compile-time for KC=128 and KC=25.
    constexpr int KCE = (KC - 2) & ~1;      // 126 for KC=128, 22 for KC=25
    #pragma unroll 2
    for (int kc = 0; kc < KCE; ++kc) {
        const int s = kc & 1;
        if (s == 0) { MFMA_SLOT(0); } else { MFMA_SLOT(1); }
        ap += astride; bp += bstride;
        if (s == 0) { LOAD_SLOT(0); } else { LOAD_SLOT(1); }
    }

    if constexpr ((KC & 1) == 0) {
        MFMA_SLOT(0);
        MFMA_SLOT(1);
    } else {
        MFMA_SLOT(0);                       // chunk KCE
        ap += astride; bp += bstride;
        LOAD_SLOT(0);                       // chunk KCE+2 -> slot 0
        MFMA_SLOT(1);                       // chunk KCE+1
        MFMA_SLOT(0);                       // chunk KCE+2
    }

    // epilogue: C/D layout col=lane&31, row=(r&3)+8*(r>>2)+4*(lane>>5)
    const int col = lane & 31;
    const int rb  = (lane >> 5) << 2;
    const int n_g = by * 64 + (wave & 1) * 32 + col;
    #pragma unroll
    for (int s = 0; s < 2; ++s) {
        const int m_base = bx * 128 + (msb + s) * 32;
        #pragma unroll
        for (int r = 0; r < 16; ++r) {
            int row = (r & 3) + 8 * (r >> 2) + rb;
            long long v = 0;
            #pragma unroll
            for (int d = 3; d >= 0; --d) v = (v << 8) + (long long)acc[s][d][r];
            C[(size_t)(m_base + row) * HIDDEN + n_g] = (double)v * scale;
        }
    }
}

// ---------------- layer 1 LIF: f64 currents, spikes -> A-fragments ---------
__global__ __launch_bounds__(256) void lif1_kernel(const double* __restrict__ CUR,
                                                   uint8_t* __restrict__ AF,
                                                   float* __restrict__ out1) {
    int e = blockIdx.x * 256 + threadIdx.x;
    int b = e >> 12;
    int j = e & 4095;
    int kc = j >> 5;
    int lane = (b & 31) | (((j >> 4) & 1) << 5);
    size_t base = (((size_t)(kc * MB_CNT + (b >> 5)) * 64 + lane) << 4) + (j & 15);
    double v = 0.0;
    int cnt = 0;
    #pragma unroll
    for (int t = 0; t < T_STEPS; ++t) {
        double cur = CUR[(size_t)t * N1 + e];
        v = __dadd_rn(__dmul_rn(v, 0.99), cur);
        int s = (v >= 0.5) ? 1 : 0;
        cnt += s;
        v = s ? 0.0 : v;
        AF[base + (size_t)t * 2048] = (uint8_t)s;
    }
    out1[e] = (float)cnt / 30.0f;
}

// ---------------- layer 2 LIF in fp64 (unchanged, passing) -----------------
__global__ __launch_bounds__(256) void lif2_kernel(const double* __restrict__ CUR,
                                                   float* __restrict__ out2) {
    int e = blockIdx.x * 256 + threadIdx.x;
    double v = 0.0;
    int cnt = 0;
    #pragma unroll
    for (int t = 0; t < T_STEPS; ++t) {
        double cur = CUR[(size_t)t * N1 + e];
        v = __dadd_rn(__dmul_rn(v, 0.99), cur);
        int s = (v >= 0.5) ? 1 : 0;
        cnt += s;
        v = s ? 0.0 : v;
    }
    out2[e] = (float)cnt / 30.0f;
}

extern "C" void kernel_launch(void* const* d_in, const int* in_sizes, int n_in,
                              void* d_out, int out_size, void* d_ws, size_t ws_size,
                              hipStream_t stream) {
    const float* x  = (const float*)d_in[0];
    const float* W1 = (const float*)d_in[1];   // 784 x 4096
    const float* W2 = (const float*)d_in[2];   // 4096 x 4096
    float* out = (float*)d_out;
    char*  ws  = (char*)d_ws;

    // workspace (~153 MB):
    // [maxbits 256B][AF1 1.54MB][BF1 12.8MB][AF2 7.86MB][BF2 64MB][CURd 62.9MB]
    const size_t AF1_SZ = (size_t)KC1 * MB_CNT * 1024;           // 1,536,000
    const size_t BF1_SZ = (size_t)128 * KC1 * NDIG * 1024;       // 12.8 MB
    const size_t AF2_SZ = (size_t)KC2 * MB_CNT * 1024;           // 7.86 MB
    const size_t BF2_SZ = (size_t)128 * KC2 * NDIG * 1024;       // 64 MB
    unsigned* maxbits = (unsigned*)ws;
    uint8_t*  AF1 = (uint8_t*)(ws + 256);
    int8_t*   BF1 = (int8_t*)(AF1 + AF1_SZ);
    uint8_t*  AF2 = (uint8_t*)(BF1 + BF1_SZ);
    int8_t*   BF2 = (int8_t*)(AF2 + AF2_SZ);
    double*   CURd = (double*)((char*)BF2 + BF2_SZ);

    float* out0 = out;
    float* out1 = out + N0;
    float* out2 = out + N0 + N1;

    hipMemsetAsync(maxbits, 0, 4, stream);
    hipMemsetAsync(AF1, 0, AF1_SZ, stream);   // K-padding rows 784..799 stay 0
    max_kernel <<<(N0 + 255) / 256, 256, 0, stream>>>(x, maxbits);
    lif0_kernel<<<dim3(4, BATCH), 256, 0, stream>>>(x, maxbits, AF1, out0);
    digitize_kernel<<<dim3(128, KC1), 256, 0, stream>>>(W1, BF1, INPUT_DIM, KC1,
                                                        4294967296.0);      // 2^32
    digitize_kernel<<<dim3(128, KC2), 256, 0, stream>>>(W2, BF2, HIDDEN, KC2,
                                                        8589934592.0);      // 2^33
    gemm_i8_kernel<KC1><<<960, 256, 0, stream>>>((const int8_t*)AF1, BF1, CURd,
                                                 2.3283064365386963e-10);   // 2^-32
    lif1_kernel<<<N1 / 256, 256, 0, stream>>>(CURd, AF2, out1);
    gemm_i8_kernel<KC2><<<960, 256, 0, stream>>>((const int8_t*)AF2, BF2, CURd,
                                                 1.1641532182693481e-10);   // 2^-33
    lif2_kernel<<<N1 / 256, 256, 0, stream>>>(CURd, out2);
}

// Round 4
// 305.600 us; speedup vs baseline: 1.0941x; 1.0717x over previous
//
#include <hip/hip_runtime.h>
#include <cstdint>
#include <cstddef>

#define INPUT_DIM 784
#define HIDDEN    4096
#define BATCH     64
#define T_STEPS   30
#define N0 (BATCH*INPUT_DIM)   // 50176
#define N1 (BATCH*HIDDEN)      // 262144
#define M_ROWS (T_STEPS*BATCH) // 1920
#define NDIG 4
#define MB_CNT (M_ROWS/32)     // 60
#define KC1 25                 // gemm1 k-chunks (784 padded to 800)
#define KC2 128                // gemm2 k-chunks

typedef int v4i  __attribute__((ext_vector_type(4)));
typedef int v16i __attribute__((ext_vector_type(16)));

// ---------------- max(x) reduction (unchanged, passing) --------------------
__global__ __launch_bounds__(256) void max_kernel(const float* __restrict__ x,
                                                  unsigned* __restrict__ maxbits) {
    int i = blockIdx.x * 256 + threadIdx.x;
    float v = (i < N0) ? x[i] : 0.0f;
    #pragma unroll
    for (int off = 32; off > 0; off >>= 1)
        v = fmaxf(v, __shfl_down(v, off, 64));
    __shared__ float sm[4];
    int lane = threadIdx.x & 63;
    int wv   = threadIdx.x >> 6;
    if (lane == 0) sm[wv] = v;
    __syncthreads();
    if (threadIdx.x == 0) {
        float m = fmaxf(fmaxf(sm[0], sm[1]), fmaxf(sm[2], sm[3]));
        atomicMax(maxbits, __float_as_uint(m));
    }
}

// ---------------- layer 0 LIF: same math (passing), spikes -> A-fragments --
// AF1[kc][mb][lane][16], lane=(b&31)|(((j>>4)&1)<<5), mb=2t+(b>>5), byte=j&15.
__global__ __launch_bounds__(256) void lif0_kernel(const float* __restrict__ x,
                                                   const unsigned* __restrict__ maxbits,
                                                   uint8_t* __restrict__ AF1,
                                                   float* __restrict__ out0) {
    int j = blockIdx.x * 256 + threadIdx.x;   // input-dim index
    int b = blockIdx.y;                        // batch
    if (j >= INPUT_DIM) return;
    float mx = fmaxf(__uint_as_float(*maxbits), 1e-12f);
    float xs = __fmul_rn(__fdiv_rn(x[b * INPUT_DIM + j], mx), 16.0f);
    int kc = j >> 5;
    int lane = (b & 31) | (((j >> 4) & 1) << 5);
    size_t base = (((size_t)(kc * MB_CNT + (b >> 5)) * 64 + lane) << 4) + (j & 15);
    float v = 0.0f;
    int cnt = 0;
    #pragma unroll
    for (int t = 0; t < T_STEPS; ++t) {
        v = __fadd_rn(__fmul_rn(v, 0.99f), xs);
        int s = (v >= 0.5f) ? 1 : 0;
        cnt += s;
        v = s ? 0.0f : v;
        AF1[base + (size_t)t * 2048] = (uint8_t)s;
    }
    out0[b * INPUT_DIM + j] = (float)cnt / 30.0f;
}

// ---------------- W -> 4 digit planes in MFMA B-fragment order -------------
// q = round(W * scale); 4 signed base-256 digits; per-elem err <= 1/(2*scale).
// BF[nb][kc][d][lane][16]; rows k >= Krows are zero (gemm1 K padding).
__global__ __launch_bounds__(256) void digitize_kernel(const float* __restrict__ W,
                                                       int8_t* __restrict__ BF,
                                                       int Krows, int KC, double scale) {
    __shared__ float tile[32][33];
    const int nb = blockIdx.x, kc = blockIdx.y;
    const int tid = threadIdx.x;
    {
        int r  = tid >> 3;
        int c4 = (tid & 7) << 2;
        int k  = kc * 32 + r;
        float4 w4 = make_float4(0.f, 0.f, 0.f, 0.f);
        if (k < Krows)
            w4 = *(const float4*)&W[(size_t)k * HIDDEN + nb * 32 + c4];
        tile[r][c4]     = w4.x;
        tile[r][c4 + 1] = w4.y;
        tile[r][c4 + 2] = w4.z;
        tile[r][c4 + 3] = w4.w;
    }
    __syncthreads();
    const int d    = tid >> 6;        // wave -> digit plane
    const int lane = tid & 63;
    const int nl   = lane & 31;
    const int kh   = (lane >> 5) << 4;
    char dig[16];
    #pragma unroll
    for (int jj = 0; jj < 16; ++jj) {
        double w = (double)tile[kh + jj][nl];
        long long q = __double2ll_rn(w * scale);
        int dd = 0;
        #pragma unroll
        for (int dd_i = 0; dd_i <= 3; ++dd_i) {
            dd = (int)(((q + 128) & 255) - 128);
            q = (q - (long long)dd) >> 8;
            if (dd_i == d) break;
        }
        dig[jj] = (char)dd;
    }
    *(int4*)&BF[((((size_t)nb * KC + kc) * NDIG + d) << 10) + (lane << 4)] =
        *(int4*)&dig[0];
}

// ---------------- exact i8-digit streaming GEMM (both layers) --------------
// C(1920 x 4096 f64) = A(binary) @ W, 4 digit planes. LDS-STAGED (new, R4).
//
// Post-mortem R0-R3: copy-free rotation (R1), depth-3 (R2), L2-resident
// phase mapping (R3) were ALL neutral at ~137us / MfmaUtil 40%. Demand-side
// arithmetic: reg-direct loads pull 6 KB/wave/chunk through the VMEM-L1
// return path for 293 cyc of MFMA -> 84 B/cyc/CU demanded vs ~64 B/cyc L1
// return peak; measured delivery 33.6 B/cyc -> 40% cap. No schedule fixes
// a bandwidth-oversubscribed pipe.
//
// Fix: stage each chunk's UNIQUE block data (A 4KB + B 8KB = 12KB) into LDS
// once via global_load_lds (16B direct-to-LDS), all 4 waves ds_read_b128
// their fragments (2x fan-out rides the separate LDS pipe, ~112 B/cyc).
// VMEM demand halves to 41 B/cyc/CU. Counted vmcnt(3) keeps stage(kc+1) in
// flight across barriers (T4); drain only in peeled tail.
//
// Per-iteration wait logic (per-wave, 3 gload_lds/iter, in-order retire):
//   at iter kc wait point outstanding = [stage(kc) x3, stage(kc+1) x3]
//   -> vmcnt(3) retires stage(kc). Tail: KC even peels kc=KC-2 (vmcnt 3),
//   KC-1 (vmcnt 0); KC odd peels KC-3 (3, +stage KC-1), KC-2 (3), KC-1 (0).
// LDS layout buf[2][12KB]: [0,4K)=A rows bx*4..+3, [4K,8K)=B nb0 d0..3,
// [8K,12K)=B nb0+1. All lane-major [64][16B] -> linear b128, conflict-free.
#define MFMA_GRP(A0, A1, B0, B1, B2, B3)                                        \
    acc[0][0] = __builtin_amdgcn_mfma_i32_32x32x32_i8(A0, B0, acc[0][0], 0, 0, 0); \
    acc[1][0] = __builtin_amdgcn_mfma_i32_32x32x32_i8(A1, B0, acc[1][0], 0, 0, 0); \
    acc[0][1] = __builtin_amdgcn_mfma_i32_32x32x32_i8(A0, B1, acc[0][1], 0, 0, 0); \
    acc[1][1] = __builtin_amdgcn_mfma_i32_32x32x32_i8(A1, B1, acc[1][1], 0, 0, 0); \
    acc[0][2] = __builtin_amdgcn_mfma_i32_32x32x32_i8(A0, B2, acc[0][2], 0, 0, 0); \
    acc[1][2] = __builtin_amdgcn_mfma_i32_32x32x32_i8(A1, B2, acc[1][2], 0, 0, 0); \
    acc[0][3] = __builtin_amdgcn_mfma_i32_32x32x32_i8(A0, B3, acc[0][3], 0, 0, 0); \
    acc[1][3] = __builtin_amdgcn_mfma_i32_32x32x32_i8(A1, B3, acc[1][3], 0, 0, 0)

__device__ __forceinline__ void gload16(const int8_t* g, int8_t* l) {
    __builtin_amdgcn_global_load_lds(
        (const __attribute__((address_space(1))) void*)g,
        (__attribute__((address_space(3))) void*)l, 16, 0, 0);
}

// stage chunk kc into lds[BUF]: per-thread one 16B piece of each 4KB layer.
// LDS dest is wave-uniform base (+ lane*16 added by HW); global src per-lane.
#define STAGE(BUF, KCV)                                                          \
    do {                                                                         \
        gload16(gA  + (size_t)(KCV) * astride, &lds[BUF][       (wave << 10)]);  \
        gload16(gB0 + (size_t)(KCV) * bstride, &lds[BUF][4096 + (wave << 10)]);  \
        gload16(gB1 + (size_t)(KCV) * bstride, &lds[BUF][8192 + (wave << 10)]);  \
    } while (0)

// one K-chunk: wait own stage(kc) (WN outstanding allowed), barrier (all
// waves' stage landed), read frags, lgkm-drain + barrier (reads done ->
// buf overwritable), optionally stage kc+2 into same buf, MFMA.
#define ITER(S, WN, DOSTAGE, KCV)                                                \
    do {                                                                         \
        asm volatile("s_waitcnt vmcnt(" #WN ")" ::: "memory");                   \
        __builtin_amdgcn_s_barrier();                                            \
        v4i a0 = *(const v4i*)&lds[S][ msb      * 1024 + (lane << 4)];           \
        v4i a1 = *(const v4i*)&lds[S][(msb + 1) * 1024 + (lane << 4)];           \
        v4i b0 = *(const v4i*)&lds[S][4096 + ((wave & 1) << 12) +        (lane << 4)]; \
        v4i b1 = *(const v4i*)&lds[S][4096 + ((wave & 1) << 12) + 1024 + (lane << 4)]; \
        v4i b2 = *(const v4i*)&lds[S][4096 + ((wave & 1) << 12) + 2048 + (lane << 4)]; \
        v4i b3 = *(const v4i*)&lds[S][4096 + ((wave & 1) << 12) + 3072 + (lane << 4)]; \
        asm volatile("s_waitcnt lgkmcnt(0)" ::: "memory");                       \
        __builtin_amdgcn_s_barrier();                                            \
        if (DOSTAGE) { STAGE(S, (KCV) + 2); }                                    \
        MFMA_GRP(a0, a1, b0, b1, b2, b3);                                        \
    } while (0)

template <int KC>
__global__ __launch_bounds__(256, 2) void gemm_i8_kernel(const int8_t* __restrict__ AF,
                                                         const int8_t* __restrict__ BF,
                                                         double* __restrict__ C,
                                                         double scale) {
    __shared__ int8_t lds[2][12288];
    const int tid  = threadIdx.x;
    const int wave = tid >> 6, lane = tid & 63;
    const int i  = blockIdx.x;
    // phase-grouped XCD mapping (R3): two dispatch phases of 480; per phase
    // each XCD owns 4 by-windows = 4MB of B (L2-resident).
    const int p  = (i >= 480) ? 1 : 0;
    const int j  = i - p * 480;
    const int bx = j >> 5;                                   // 0..14
    const int by = p * 32 + ((j & 7) << 2) + ((j >> 3) & 3); // 0..63
    const int nb0 = by * 2;
    const int msb = (wave >> 1) * 2;

    const int astride = MB_CNT * 1024;      // 61440 B per k-chunk in AF
    const int bstride = NDIG * 1024;        // 4096  B per k-chunk in BF panel
    // per-thread 16B staging sources (tid*16 = wave*1024 + lane*16)
    const int8_t* gA  = AF + (((size_t)(bx * 4) * 64) << 4) + tid * 16;
    const int8_t* gB0 = BF + (((size_t)nb0 * KC * NDIG) << 10) + tid * 16;
    const int8_t* gB1 = gB0 + ((size_t)KC * NDIG << 10);

    v16i acc[2][4] = {};

    STAGE(0, 0);                            // chunk 0 -> buf 0
    STAGE(1, 1);                            // chunk 1 -> buf 1

    constexpr int KCM = (KC - 2) & ~1;      // 126 for KC=128, 22 for KC=25
    for (int kc = 0; kc < KCM; kc += 2) {
        ITER(0, 3, 1, kc);                  // consume kc,   stage kc+2
        ITER(1, 3, 1, kc + 1);              // consume kc+1, stage kc+3
    }
    if constexpr ((KC & 1) == 0) {
        ITER(0, 3, 0, KC - 2);              // outstanding [KC-2,KC-1] -> ok
        ITER(1, 0, 0, KC - 1);              // last: full drain
    } else {
        ITER(0, 3, 1, KC - 3);              // stage KC-1 -> buf 0
        ITER(1, 3, 0, KC - 2);              // outstanding [KC-2,KC-1] -> ok
        ITER(0, 0, 0, KC - 1);              // last: full drain
    }

    // epilogue: C/D layout col=lane&31, row=(r&3)+8*(r>>2)+4*(lane>>5)
    const int col = lane & 31;
    const int rb  = (lane >> 5) << 2;
    const int n_g = by * 64 + (wave & 1) * 32 + col;
    #pragma unroll
    for (int s = 0; s < 2; ++s) {
        const int m_base = bx * 128 + (msb + s) * 32;
        #pragma unroll
        for (int r = 0; r < 16; ++r) {
            int row = (r & 3) + 8 * (r >> 2) + rb;
            long long v = 0;
            #pragma unroll
            for (int d = 3; d >= 0; --d) v = (v << 8) + (long long)acc[s][d][r];
            C[(size_t)(m_base + row) * HIDDEN + n_g] = (double)v * scale;
        }
    }
}

// ---------------- layer 1 LIF: f64 currents, spikes -> A-fragments ---------
__global__ __launch_bounds__(256) void lif1_kernel(const double* __restrict__ CUR,
                                                   uint8_t* __restrict__ AF,
                                                   float* __restrict__ out1) {
    int e = blockIdx.x * 256 + threadIdx.x;
    int b = e >> 12;
    int j = e & 4095;
    int kc = j >> 5;
    int lane = (b & 31) | (((j >> 4) & 1) << 5);
    size_t base = (((size_t)(kc * MB_CNT + (b >> 5)) * 64 + lane) << 4) + (j & 15);
    double v = 0.0;
    int cnt = 0;
    #pragma unroll
    for (int t = 0; t < T_STEPS; ++t) {
        double cur = CUR[(size_t)t * N1 + e];
        v = __dadd_rn(__dmul_rn(v, 0.99), cur);
        int s = (v >= 0.5) ? 1 : 0;
        cnt += s;
        v = s ? 0.0 : v;
        AF[base + (size_t)t * 2048] = (uint8_t)s;
    }
    out1[e] = (float)cnt / 30.0f;
}

// ---------------- layer 2 LIF in fp64 (unchanged, passing) -----------------
__global__ __launch_bounds__(256) void lif2_kernel(const double* __restrict__ CUR,
                                                   float* __restrict__ out2) {
    int e = blockIdx.x * 256 + threadIdx.x;
    double v = 0.0;
    int cnt = 0;
    #pragma unroll
    for (int t = 0; t < T_STEPS; ++t) {
        double cur = CUR[(size_t)t * N1 + e];
        v = __dadd_rn(__dmul_rn(v, 0.99), cur);
        int s = (v >= 0.5) ? 1 : 0;
        cnt += s;
        v = s ? 0.0 : v;
    }
    out2[e] = (float)cnt / 30.0f;
}

extern "C" void kernel_launch(void* const* d_in, const int* in_sizes, int n_in,
                              void* d_out, int out_size, void* d_ws, size_t ws_size,
                              hipStream_t stream) {
    const float* x  = (const float*)d_in[0];
    const float* W1 = (const float*)d_in[1];   // 784 x 4096
    const float* W2 = (const float*)d_in[2];   // 4096 x 4096
    float* out = (float*)d_out;
    char*  ws  = (char*)d_ws;

    // workspace (~153 MB):
    // [maxbits 256B][AF1 1.54MB][BF1 12.8MB][AF2 7.86MB][BF2 64MB][CURd 62.9MB]
    const size_t AF1_SZ = (size_t)KC1 * MB_CNT * 1024;           // 1,536,000
    const size_t BF1_SZ = (size_t)128 * KC1 * NDIG * 1024;       // 12.8 MB
    const size_t AF2_SZ = (size_t)KC2 * MB_CNT * 1024;           // 7.86 MB
    const size_t BF2_SZ = (size_t)128 * KC2 * NDIG * 1024;       // 64 MB
    unsigned* maxbits = (unsigned*)ws;
    uint8_t*  AF1 = (uint8_t*)(ws + 256);
    int8_t*   BF1 = (int8_t*)(AF1 + AF1_SZ);
    uint8_t*  AF2 = (uint8_t*)(BF1 + BF1_SZ);
    int8_t*   BF2 = (int8_t*)(AF2 + AF2_SZ);
    double*   CURd = (double*)((char*)BF2 + BF2_SZ);

    float* out0 = out;
    float* out1 = out + N0;
    float* out2 = out + N0 + N1;

    hipMemsetAsync(maxbits, 0, 4, stream);
    hipMemsetAsync(AF1, 0, AF1_SZ, stream);   // K-padding rows 784..799 stay 0
    max_kernel <<<(N0 + 255) / 256, 256, 0, stream>>>(x, maxbits);
    lif0_kernel<<<dim3(4, BATCH), 256, 0, stream>>>(x, maxbits, AF1, out0);
    digitize_kernel<<<dim3(128, KC1), 256, 0, stream>>>(W1, BF1, INPUT_DIM, KC1,
                                                        4294967296.0);      // 2^32
    digitize_kernel<<<dim3(128, KC2), 256, 0, stream>>>(W2, BF2, HIDDEN, KC2,
                                                        8589934592.0);      // 2^33
    gemm_i8_kernel<KC1><<<960, 256, 0, stream>>>((const int8_t*)AF1, BF1, CURd,
                                                 2.3283064365386963e-10);   // 2^-32
    lif1_kernel<<<N1 / 256, 256, 0, stream>>>(CURd, AF2, out1);
    gemm_i8_kernel<KC2><<<960, 256, 0, stream>>>((const int8_t*)AF2, BF2, CURd,
                                                 1.1641532182693481e-10);   // 2^-33
    lif2_kernel<<<N1 / 256, 256, 0, stream>>>(CURd, out2);
}

// Round 5
// 302.355 us; speedup vs baseline: 1.1059x; 1.0107x over previous
//
#include <hip/hip_runtime.h>
#include <cstdint>
#include <cstddef>

#define INPUT_DIM 784
#define HIDDEN    4096
#define BATCH     64
#define T_STEPS   30
#define N0 (BATCH*INPUT_DIM)   // 50176
#define N1 (BATCH*HIDDEN)      // 262144
#define M_ROWS (T_STEPS*BATCH) // 1920
#define NDIG 4
#define MB_CNT (M_ROWS/32)     // 60
#define KC1 25                 // gemm1 k-chunks (784 padded to 800)
#define KC2 128                // gemm2 k-chunks

typedef int v4i  __attribute__((ext_vector_type(4)));
typedef int v16i __attribute__((ext_vector_type(16)));

// ---------------- max(x) reduction (unchanged, passing) --------------------
__global__ __launch_bounds__(256) void max_kernel(const float* __restrict__ x,
                                                  unsigned* __restrict__ maxbits) {
    int i = blockIdx.x * 256 + threadIdx.x;
    float v = (i < N0) ? x[i] : 0.0f;
    #pragma unroll
    for (int off = 32; off > 0; off >>= 1)
        v = fmaxf(v, __shfl_down(v, off, 64));
    __shared__ float sm[4];
    int lane = threadIdx.x & 63;
    int wv   = threadIdx.x >> 6;
    if (lane == 0) sm[wv] = v;
    __syncthreads();
    if (threadIdx.x == 0) {
        float m = fmaxf(fmaxf(sm[0], sm[1]), fmaxf(sm[2], sm[3]));
        atomicMax(maxbits, __float_as_uint(m));
    }
}

// ---------------- layer 0 LIF: same math (passing), spikes -> A-fragments --
// AF1[kc][mb][lane][16], lane=(b&31)|(((j>>4)&1)<<5), mb=2t+(b>>5), byte=j&15.
__global__ __launch_bounds__(256) void lif0_kernel(const float* __restrict__ x,
                                                   const unsigned* __restrict__ maxbits,
                                                   uint8_t* __restrict__ AF1,
                                                   float* __restrict__ out0) {
    int j = blockIdx.x * 256 + threadIdx.x;   // input-dim index
    int b = blockIdx.y;                        // batch
    if (j >= INPUT_DIM) return;
    float mx = fmaxf(__uint_as_float(*maxbits), 1e-12f);
    float xs = __fmul_rn(__fdiv_rn(x[b * INPUT_DIM + j], mx), 16.0f);
    int kc = j >> 5;
    int lane = (b & 31) | (((j >> 4) & 1) << 5);
    size_t base = (((size_t)(kc * MB_CNT + (b >> 5)) * 64 + lane) << 4) + (j & 15);
    float v = 0.0f;
    int cnt = 0;
    #pragma unroll
    for (int t = 0; t < T_STEPS; ++t) {
        v = __fadd_rn(__fmul_rn(v, 0.99f), xs);
        int s = (v >= 0.5f) ? 1 : 0;
        cnt += s;
        v = s ? 0.0f : v;
        AF1[base + (size_t)t * 2048] = (uint8_t)s;
    }
    out0[b * INPUT_DIM + j] = (float)cnt / 30.0f;
}

// ---------------- W -> 4 digit planes in MFMA B-fragment order -------------
// q = round(W * scale); 4 signed base-256 digits; per-elem err <= 1/(2*scale).
// BF[nb][kc][d][lane][16]; rows k >= Krows are zero (gemm1 K padding).
__global__ __launch_bounds__(256) void digitize_kernel(const float* __restrict__ W,
                                                       int8_t* __restrict__ BF,
                                                       int Krows, int KC, double scale) {
    __shared__ float tile[32][33];
    const int nb = blockIdx.x, kc = blockIdx.y;
    const int tid = threadIdx.x;
    {
        int r  = tid >> 3;
        int c4 = (tid & 7) << 2;
        int k  = kc * 32 + r;
        float4 w4 = make_float4(0.f, 0.f, 0.f, 0.f);
        if (k < Krows)
            w4 = *(const float4*)&W[(size_t)k * HIDDEN + nb * 32 + c4];
        tile[r][c4]     = w4.x;
        tile[r][c4 + 1] = w4.y;
        tile[r][c4 + 2] = w4.z;
        tile[r][c4 + 3] = w4.w;
    }
    __syncthreads();
    const int d    = tid >> 6;        // wave -> digit plane
    const int lane = tid & 63;
    const int nl   = lane & 31;
    const int kh   = (lane >> 5) << 4;
    char dig[16];
    #pragma unroll
    for (int jj = 0; jj < 16; ++jj) {
        double w = (double)tile[kh + jj][nl];
        long long q = __double2ll_rn(w * scale);
        int dd = 0;
        #pragma unroll
        for (int dd_i = 0; dd_i <= 3; ++dd_i) {
            dd = (int)(((q + 128) & 255) - 128);
            q = (q - (long long)dd) >> 8;
            if (dd_i == d) break;
        }
        dig[jj] = (char)dd;
    }
    *(int4*)&BF[((((size_t)nb * KC + kc) * NDIG + d) << 10) + (lane << 4)] =
        *(int4*)&dig[0];
}

// ---------------- exact i8-digit streaming GEMM (both layers) --------------
// C(1920 x 4096 f64) = A(binary) @ W, 4 digit planes. LDS ring-4 (R5).
//
// R4 post-mortem: LDS staging was the right lever (137->122.7us, MfmaUtil
// 40->48.6, FETCH 136->109MB) -- first matched prediction. Remaining cap is
// the 2-barrier + lgkmcnt(0)-drain per chunk (the classic 2-phase stall
// regime): the 2nd barrier existed only because with 2 buffers the staged
// buffer is the one just read.
//
// R5: RING-4 buffers (4 x 12KB = 48KB/block, 2 blocks = 96KB/CU). Iter kc
// reads buf kc%4, stages chunk kc+3 into buf (kc+3)%4 -- never the buffer
// being read. ONE barrier per iter, no lgkm drain: a wave reaches
// barrier(kc) only after its iter-(kc-1) MFMAs issued, which required the
// ds_read data delivered, so the buf staged at iter kc (last read at kc-1)
// is free. Counted vmcnt(6) = 2 stages (6 loads) stay in flight across the
// barrier; stage(kc) was issued 3 iters (~2000 cyc) earlier -> wait ~0.
// sched_barrier(0) fences both sides of vmcnt+s_barrier (rule: compiler
// hoists reg-only MFMA past asm waitcnt otherwise).
//
// Wait-count derivation (3 gload_lds per stage, in-order vmcnt retire):
// at iter kcv wait, outstanding = stages kcv..min(kcv+2,KC-1) ->
// vmcnt = 3*min(2, KC-1-kcv): 6 for kcv<=KC-3, 3 at KC-2, 0 at KC-1.
// KC=128 tail (KCM=124): iters 124(stage 127,w6) 125(w6) 126(w3) 127(w0).
// KC=25  tail (KCM=20): 20(stage23,w6) 21(stage24,w6) 22(w6) 23(w3) 24(w0).
#define MFMA_GRP(A0, A1, B0, B1, B2, B3)                                        \
    acc[0][0] = __builtin_amdgcn_mfma_i32_32x32x32_i8(A0, B0, acc[0][0], 0, 0, 0); \
    acc[1][0] = __builtin_amdgcn_mfma_i32_32x32x32_i8(A1, B0, acc[1][0], 0, 0, 0); \
    acc[0][1] = __builtin_amdgcn_mfma_i32_32x32x32_i8(A0, B1, acc[0][1], 0, 0, 0); \
    acc[1][1] = __builtin_amdgcn_mfma_i32_32x32x32_i8(A1, B1, acc[1][1], 0, 0, 0); \
    acc[0][2] = __builtin_amdgcn_mfma_i32_32x32x32_i8(A0, B2, acc[0][2], 0, 0, 0); \
    acc[1][2] = __builtin_amdgcn_mfma_i32_32x32x32_i8(A1, B2, acc[1][2], 0, 0, 0); \
    acc[0][3] = __builtin_amdgcn_mfma_i32_32x32x32_i8(A0, B3, acc[0][3], 0, 0, 0); \
    acc[1][3] = __builtin_amdgcn_mfma_i32_32x32x32_i8(A1, B3, acc[1][3], 0, 0, 0)

__device__ __forceinline__ void gload16(const int8_t* g, int8_t* l) {
    __builtin_amdgcn_global_load_lds(
        (const __attribute__((address_space(1))) void*)g,
        (__attribute__((address_space(3))) void*)l, 16, 0, 0);
}

// stage chunk KCV into lds[BUF]: per-thread one 16B piece of each 4KB layer.
// LDS dest is wave-uniform base (+ lane*16 added by HW); global src per-lane.
#define STAGE(BUF, KCV)                                                          \
    do {                                                                         \
        gload16(gA  + (size_t)(KCV) * astride, &lds[BUF][       (wave << 10)]);  \
        gload16(gB0 + (size_t)(KCV) * bstride, &lds[BUF][4096 + (wave << 10)]);  \
        gload16(gB1 + (size_t)(KCV) * bstride, &lds[BUF][8192 + (wave << 10)]);  \
    } while (0)

// one K-chunk: sched-fence, wait own stage(kcv) (WN outstanding allowed) +
// rendezvous (all waves' stage landed), sched-fence, read frags, stage
// chunk kcv+3 into buf (S+3)&3 (not being read), MFMA (compiler inserts
// fine-grained lgkmcnt before use).
#define ITER(S, WN, DOSTAGE, KCV)                                                \
    do {                                                                         \
        __builtin_amdgcn_sched_barrier(0);                                       \
        asm volatile("s_waitcnt vmcnt(" #WN ")\n\ts_barrier" ::: "memory");      \
        __builtin_amdgcn_sched_barrier(0);                                       \
        v4i a0 = *(const v4i*)&lds[S][ msb      * 1024 + (lane << 4)];           \
        v4i a1 = *(const v4i*)&lds[S][(msb + 1) * 1024 + (lane << 4)];           \
        v4i b0 = *(const v4i*)&lds[S][4096 + ((wave & 1) << 12) +        (lane << 4)]; \
        v4i b1 = *(const v4i*)&lds[S][4096 + ((wave & 1) << 12) + 1024 + (lane << 4)]; \
        v4i b2 = *(const v4i*)&lds[S][4096 + ((wave & 1) << 12) + 2048 + (lane << 4)]; \
        v4i b3 = *(const v4i*)&lds[S][4096 + ((wave & 1) << 12) + 3072 + (lane << 4)]; \
        if (DOSTAGE) { STAGE((S + 3) & 3, (KCV) + 3); }                          \
        MFMA_GRP(a0, a1, b0, b1, b2, b3);                                        \
    } while (0)

template <int KC>
__global__ __launch_bounds__(256, 2) void gemm_i8_kernel(const int8_t* __restrict__ AF,
                                                         const int8_t* __restrict__ BF,
                                                         double* __restrict__ C,
                                                         double scale) {
    __shared__ int8_t lds[4][12288];
    const int tid  = threadIdx.x;
    const int wave = tid >> 6, lane = tid & 63;
    const int i  = blockIdx.x;
    // phase-grouped XCD mapping (R3): two dispatch phases of 480; per phase
    // each XCD owns 4 by-windows = 4MB of B (L2-resident).
    const int p  = (i >= 480) ? 1 : 0;
    const int j  = i - p * 480;
    const int bx = j >> 5;                                   // 0..14
    const int by = p * 32 + ((j & 7) << 2) + ((j >> 3) & 3); // 0..63
    const int nb0 = by * 2;
    const int msb = (wave >> 1) * 2;

    const int astride = MB_CNT * 1024;      // 61440 B per k-chunk in AF
    const int bstride = NDIG * 1024;        // 4096  B per k-chunk in BF panel
    // per-thread 16B staging sources (tid*16 = wave*1024 + lane*16)
    const int8_t* gA  = AF + (((size_t)(bx * 4) * 64) << 4) + tid * 16;
    const int8_t* gB0 = BF + (((size_t)nb0 * KC * NDIG) << 10) + tid * 16;
    const int8_t* gB1 = gB0 + ((size_t)KC * NDIG << 10);

    v16i acc[2][4] = {};

    STAGE(0, 0);                            // chunk 0 -> buf 0
    STAGE(1, 1);                            // chunk 1 -> buf 1
    STAGE(2, 2);                            // chunk 2 -> buf 2

    constexpr int KCM = ((KC - 4) / 4) * 4; // 124 for KC=128, 20 for KC=25
    for (int kc = 0; kc < KCM; kc += 4) {
        ITER(0, 6, 1, kc);                  // read buf0, stage kc+3 -> buf3
        ITER(1, 6, 1, kc + 1);              // read buf1, stage kc+4 -> buf0
        ITER(2, 6, 1, kc + 2);              // read buf2, stage kc+5 -> buf1
        ITER(3, 6, 1, kc + 3);              // read buf3, stage kc+6 -> buf2
    }
    if constexpr ((KC & 3) == 0) {          // KC=128
        ITER(0, 6, 1, KCM);                 // stage KC-1 -> buf3
        ITER(1, 6, 0, KCM + 1);
        ITER(2, 3, 0, KCM + 2);
        ITER(3, 0, 0, KCM + 3);
    } else {                                // KC=25 (KC%4==1)
        ITER(0, 6, 1, KCM);                 // kcv=20, stage 23 -> buf3
        ITER(1, 6, 1, KCM + 1);             // kcv=21, stage 24 -> buf0
        ITER(2, 6, 0, KCM + 2);             // kcv=22
        ITER(3, 3, 0, KCM + 3);             // kcv=23
        ITER(0, 0, 0, KCM + 4);             // kcv=24
    }

    // epilogue: C/D layout col=lane&31, row=(r&3)+8*(r>>2)+4*(lane>>5)
    const int col = lane & 31;
    const int rb  = (lane >> 5) << 2;
    const int n_g = by * 64 + (wave & 1) * 32 + col;
    #pragma unroll
    for (int s = 0; s < 2; ++s) {
        const int m_base = bx * 128 + (msb + s) * 32;
        #pragma unroll
        for (int r = 0; r < 16; ++r) {
            int row = (r & 3) + 8 * (r >> 2) + rb;
            long long v = 0;
            #pragma unroll
            for (int d = 3; d >= 0; --d) v = (v << 8) + (long long)acc[s][d][r];
            C[(size_t)(m_base + row) * HIDDEN + n_g] = (double)v * scale;
        }
    }
}

// ---------------- layer 1 LIF: f64 currents, spikes -> A-fragments ---------
__global__ __launch_bounds__(256) void lif1_kernel(const double* __restrict__ CUR,
                                                   uint8_t* __restrict__ AF,
                                                   float* __restrict__ out1) {
    int e = blockIdx.x * 256 + threadIdx.x;
    int b = e >> 12;
    int j = e & 4095;
    int kc = j >> 5;
    int lane = (b & 31) | (((j >> 4) & 1) << 5);
    size_t base = (((size_t)(kc * MB_CNT + (b >> 5)) * 64 + lane) << 4) + (j & 15);
    double v = 0.0;
    int cnt = 0;
    #pragma unroll
    for (int t = 0; t < T_STEPS; ++t) {
        double cur = CUR[(size_t)t * N1 + e];
        v = __dadd_rn(__dmul_rn(v, 0.99), cur);
        int s = (v >= 0.5) ? 1 : 0;
        cnt += s;
        v = s ? 0.0 : v;
        AF[base + (size_t)t * 2048] = (uint8_t)s;
    }
    out1[e] = (float)cnt / 30.0f;
}

// ---------------- layer 2 LIF in fp64 (unchanged, passing) -----------------
__global__ __launch_bounds__(256) void lif2_kernel(const double* __restrict__ CUR,
                                                   float* __restrict__ out2) {
    int e = blockIdx.x * 256 + threadIdx.x;
    double v = 0.0;
    int cnt = 0;
    #pragma unroll
    for (int t = 0; t < T_STEPS; ++t) {
        double cur = CUR[(size_t)t * N1 + e];
        v = __dadd_rn(__dmul_rn(v, 0.99), cur);
        int s = (v >= 0.5) ? 1 : 0;
        cnt += s;
        v = s ? 0.0 : v;
    }
    out2[e] = (float)cnt / 30.0f;
}

extern "C" void kernel_launch(void* const* d_in, const int* in_sizes, int n_in,
                              void* d_out, int out_size, void* d_ws, size_t ws_size,
                              hipStream_t stream) {
    const float* x  = (const float*)d_in[0];
    const float* W1 = (const float*)d_in[1];   // 784 x 4096
    const float* W2 = (const float*)d_in[2];   // 4096 x 4096
    float* out = (float*)d_out;
    char*  ws  = (char*)d_ws;

    // workspace (~153 MB):
    // [maxbits 256B][AF1 1.54MB][BF1 12.8MB][AF2 7.86MB][BF2 64MB][CURd 62.9MB]
    const size_t AF1_SZ = (size_t)KC1 * MB_CNT * 1024;           // 1,536,000
    const size_t BF1_SZ = (size_t)128 * KC1 * NDIG * 1024;       // 12.8 MB
    const size_t AF2_SZ = (size_t)KC2 * MB_CNT * 1024;           // 7.86 MB
    const size_t BF2_SZ = (size_t)128 * KC2 * NDIG * 1024;       // 64 MB
    unsigned* maxbits = (unsigned*)ws;
    uint8_t*  AF1 = (uint8_t*)(ws + 256);
    int8_t*   BF1 = (int8_t*)(AF1 + AF1_SZ);
    uint8_t*  AF2 = (uint8_t*)(BF1 + BF1_SZ);
    int8_t*   BF2 = (int8_t*)(AF2 + AF2_SZ);
    double*   CURd = (double*)((char*)BF2 + BF2_SZ);

    float* out0 = out;
    float* out1 = out + N0;
    float* out2 = out + N0 + N1;

    hipMemsetAsync(maxbits, 0, 4, stream);
    hipMemsetAsync(AF1, 0, AF1_SZ, stream);   // K-padding rows 784..799 stay 0
    max_kernel <<<(N0 + 255) / 256, 256, 0, stream>>>(x, maxbits);
    lif0_kernel<<<dim3(4, BATCH), 256, 0, stream>>>(x, maxbits, AF1, out0);
    digitize_kernel<<<dim3(128, KC1), 256, 0, stream>>>(W1, BF1, INPUT_DIM, KC1,
                                                        4294967296.0);      // 2^32
    digitize_kernel<<<dim3(128, KC2), 256, 0, stream>>>(W2, BF2, HIDDEN, KC2,
                                                        8589934592.0);      // 2^33
    gemm_i8_kernel<KC1><<<960, 256, 0, stream>>>((const int8_t*)AF1, BF1, CURd,
                                                 2.3283064365386963e-10);   // 2^-32
    lif1_kernel<<<N1 / 256, 256, 0, stream>>>(CURd, AF2, out1);
    gemm_i8_kernel<KC2><<<960, 256, 0, stream>>>((const int8_t*)AF2, BF2, CURd,
                                                 1.1641532182693481e-10);   // 2^-33
    lif2_kernel<<<N1 / 256, 256, 0, stream>>>(CURd, out2);
}